// Round 1
// baseline (610.595 us; speedup 1.0000x reference)
//
#include <hip/hip_runtime.h>

// ---------------------------------------------------------------------------
// Problem: B=8, N=1024, F=320, H=5 (heads collapse: at = (Q·K^T)/8)
//   1) qk = h @ Wqk + bqk  -> deinterleave into Q, K  (8192x640x320 GEMM)
//   2) at = Q @ K^T * 0.125 per batch                 (8x 1024x1024x320 NT GEMM)
//   3) per row: thr = 171st largest; mask (<thr -> -1e-7); softmax(x/0.3)
//   4) of = attn @ h per batch                        (8x 1024x320x1024 NN GEMM)
//   5) out = of @ weight + bias                       (8192x320x320 NN GEMM)
// All fp32 vector-ALU (no fp32 MFMA on CDNA4). Baseline round.
// ---------------------------------------------------------------------------

#define TILE 64
#define BK 16

template <bool TRANSB, bool SPLIT_QK, int BPAD>
__global__ __launch_bounds__(256) void gemm64(
    const float* __restrict__ A, const float* __restrict__ B,
    float* __restrict__ C, float* __restrict__ C2,
    const float* __restrict__ bias,
    int M, int N, int K, int lda, int ldb, int ldc,
    long sA, long sB, long sC, float alpha)
{
    __shared__ float As[TILE][BK + 1];     // [m][k], +1 pad
    __shared__ float Bs[BK][TILE + BPAD];  // [k][n]

    const int bx = blockIdx.x, by = blockIdx.y, bz = blockIdx.z;
    A += (long)bz * sA;
    B += (long)bz * sB;
    C += (long)bz * sC;

    const int tx = threadIdx.x;  // 0..15
    const int ty = threadIdx.y;  // 0..15
    const int tid = ty * 16 + tx;

    const int row0 = by * TILE + ty * 4;
    const int col0 = bx * TILE + tx * 4;

    float acc[4][4] = {};

    const int aRow = tid >> 2;        // 0..63
    const int aK   = (tid & 3) * 4;   // 0,4,8,12

    for (int k0 = 0; k0 < K; k0 += BK) {
        // A tile: 64(m) x 16(k), float4 along k
        {
            const float4 av = *reinterpret_cast<const float4*>(
                &A[(long)(by * TILE + aRow) * lda + k0 + aK]);
            As[aRow][aK + 0] = av.x;
            As[aRow][aK + 1] = av.y;
            As[aRow][aK + 2] = av.z;
            As[aRow][aK + 3] = av.w;
        }
        if (!TRANSB) {
            // B tile: 16(k) x 64(n), float4 along n
            const int bK = tid >> 4;          // 0..15
            const int bC = (tid & 15) * 4;    // 0..60
            const float4 bv = *reinterpret_cast<const float4*>(
                &B[(long)(k0 + bK) * ldb + bx * TILE + bC]);
            *reinterpret_cast<float4*>(&Bs[bK][bC]) = bv;
        } else {
            // B is N x K row-major; need Bs[k][n]
            const int bN = tid >> 2;          // 0..63
            const int bK = (tid & 3) * 4;     // 0,4,8,12
            const float4 bv = *reinterpret_cast<const float4*>(
                &B[(long)(bx * TILE + bN) * ldb + k0 + bK]);
            Bs[bK + 0][bN] = bv.x;
            Bs[bK + 1][bN] = bv.y;
            Bs[bK + 2][bN] = bv.z;
            Bs[bK + 3][bN] = bv.w;
        }
        __syncthreads();

        #pragma unroll
        for (int k = 0; k < BK; ++k) {
            float a[4], b[4];
            #pragma unroll
            for (int i = 0; i < 4; ++i) a[i] = As[ty * 4 + i][k];
            #pragma unroll
            for (int j = 0; j < 4; ++j) b[j] = Bs[k][tx * 4 + j];
            #pragma unroll
            for (int i = 0; i < 4; ++i)
                #pragma unroll
                for (int j = 0; j < 4; ++j)
                    acc[i][j] = fmaf(a[i], b[j], acc[i][j]);
        }
        __syncthreads();
    }

    if (!SPLIT_QK) {
        #pragma unroll
        for (int i = 0; i < 4; ++i) {
            float4 v;
            v.x = alpha * acc[i][0] + (bias ? bias[col0 + 0] : 0.f);
            v.y = alpha * acc[i][1] + (bias ? bias[col0 + 1] : 0.f);
            v.z = alpha * acc[i][2] + (bias ? bias[col0 + 2] : 0.f);
            v.w = alpha * acc[i][3] + (bias ? bias[col0 + 3] : 0.f);
            *reinterpret_cast<float4*>(&C[(long)(row0 + i) * ldc + col0]) = v;
        }
    } else {
        // qk deinterleave: even col -> Q (C), odd col -> K (C2); ld = 320
        #pragma unroll
        for (int i = 0; i < 4; ++i) {
            #pragma unroll
            for (int j = 0; j < 4; ++j) {
                const int c = col0 + j;
                const float v = acc[i][j] + bias[c];
                float* dst = (c & 1) ? C2 : C;
                dst[(long)(row0 + i) * 320 + (c >> 1)] = v;
            }
        }
    }
}

// One block per row of `at` (8192 rows, 1024 elems each).
// Bitonic sort in LDS for exact 171st-largest threshold, then masked softmax.
__global__ __launch_bounds__(1024) void topk_softmax(float* __restrict__ at)
{
    __shared__ float s[1024];
    const int tid = threadIdx.x;
    float* row = at + (long)blockIdx.x * 1024;

    const float v = row[tid];
    s[tid] = v;
    __syncthreads();

    // bitonic sort ascending
    for (int k = 2; k <= 1024; k <<= 1) {
        for (int j = k >> 1; j > 0; j >>= 1) {
            const int ixj = tid ^ j;
            if (ixj > tid) {
                const float a = s[tid], b = s[ixj];
                const bool up = ((tid & k) == 0);
                if (up ? (a > b) : (a < b)) { s[tid] = b; s[ixj] = a; }
            }
            __syncthreads();
        }
    }

    // keep = N/6 + 1 = 171 largest; threshold = smallest kept = s[1024-171]
    const float thr = s[853];
    __syncthreads();

    const float adj = (v < thr) ? -1e-7f : v;
    const float logit = adj * (1.0f / 0.3f);

    // max reduce
    s[tid] = logit;
    __syncthreads();
    for (int sft = 512; sft > 0; sft >>= 1) {
        if (tid < sft) s[tid] = fmaxf(s[tid], s[tid + sft]);
        __syncthreads();
    }
    const float m = s[0];
    __syncthreads();

    const float e = expf(logit - m);
    s[tid] = e;
    __syncthreads();
    for (int sft = 512; sft > 0; sft >>= 1) {
        if (tid < sft) s[tid] += s[tid + sft];
        __syncthreads();
    }
    const float sum = s[0];

    row[tid] = e / sum;
}

extern "C" void kernel_launch(void* const* d_in, const int* in_sizes, int n_in,
                              void* d_out, int out_size, void* d_ws, size_t ws_size,
                              hipStream_t stream) {
    (void)in_sizes; (void)n_in; (void)out_size; (void)ws_size;

    const float* h      = (const float*)d_in[0];  // 8x1024x320
    const float* Wqk    = (const float*)d_in[1];  // 320x640
    const float* bqk    = (const float*)d_in[2];  // 640
    const float* weight = (const float*)d_in[3];  // 320x320
    const float* bias   = (const float*)d_in[4];  // 320
    float* out = (float*)d_out;                   // 8x1024x320

    float* Q    = (float*)d_ws;          // 8192*320
    float* Kb   = Q  + 2621440;          // 8192*320
    float* at   = Kb + 2621440;          // 8*1024*1024
    float* of   = at + 8388608;          // 8192*320

    const dim3 blk(16, 16);

    // 1) qk = h @ Wqk + bqk, split -> Q,K   (M=8192,N=640,K=320)
    gemm64<false, true, 0><<<dim3(640 / TILE, 8192 / TILE, 1), blk, 0, stream>>>(
        h, Wqk, Q, Kb, bqk, 8192, 640, 320, 320, 640, 320, 0, 0, 0, 1.0f);

    // 2) at = 0.125 * Q @ K^T per batch    (M=1024,N=1024,K=320)
    gemm64<true, false, 1><<<dim3(1024 / TILE, 1024 / TILE, 8), blk, 0, stream>>>(
        Q, Kb, at, nullptr, nullptr, 1024, 1024, 320, 320, 320, 1024,
        327680, 327680, 1048576, 0.125f);

    // 3) threshold + softmax in place
    topk_softmax<<<8192, 1024, 0, stream>>>(at);

    // 4) of = attn @ h per batch           (M=1024,N=320,K=1024)
    gemm64<false, false, 0><<<dim3(320 / TILE, 1024 / TILE, 8), blk, 0, stream>>>(
        at, h, of, nullptr, nullptr, 1024, 320, 1024, 1024, 320, 320,
        1048576, 327680, 327680, 1.0f);

    // 5) out = of @ weight + bias          (M=8192,N=320,K=320)
    gemm64<false, false, 0><<<dim3(320 / TILE, 8192 / TILE, 1), blk, 0, stream>>>(
        of, weight, out, nullptr, bias, 8192, 320, 320, 320, 320, 320,
        0, 0, 0, 1.0f);
}

// Round 2
// 384.023 us; speedup vs baseline: 1.5900x; 1.5900x over previous
//
#include <hip/hip_runtime.h>

// ---------------------------------------------------------------------------
// Problem: B=8, N=1024, F=320, H=5 (heads collapse: at = (Q·K^T)/8)
//   1) qk = h @ Wqk + bqk  -> deinterleave into Q, K  (8192x640x320 GEMM)
//   2) at = Q @ K^T * 0.125 per batch                 (8x 1024x1024x320 NT GEMM)
//   3) per row: thr = 171st largest; mask (<thr -> -1e-7); softmax(x/0.3)
//   4) of = attn @ h per batch                        (8x 1024x320x1024 NN GEMM)
//   5) out = of @ weight + bias                       (8192x320x320 NN GEMM)
// R1: bitonic sort (55 barrier rounds, 16-wave blocks) -> exact 4-pass radix
//     select (≈16 barriers, 4-wave blocks). GEMMs unchanged to isolate.
// ---------------------------------------------------------------------------

#define TILE 64
#define BK 16

template <bool TRANSB, bool SPLIT_QK, int BPAD>
__global__ __launch_bounds__(256) void gemm64(
    const float* __restrict__ A, const float* __restrict__ B,
    float* __restrict__ C, float* __restrict__ C2,
    const float* __restrict__ bias,
    int M, int N, int K, int lda, int ldb, int ldc,
    long sA, long sB, long sC, float alpha)
{
    __shared__ float As[TILE][BK + 1];     // [m][k], +1 pad
    __shared__ float Bs[BK][TILE + BPAD];  // [k][n]

    const int bx = blockIdx.x, by = blockIdx.y, bz = blockIdx.z;
    A += (long)bz * sA;
    B += (long)bz * sB;
    C += (long)bz * sC;

    const int tx = threadIdx.x;  // 0..15
    const int ty = threadIdx.y;  // 0..15
    const int tid = ty * 16 + tx;

    const int row0 = by * TILE + ty * 4;
    const int col0 = bx * TILE + tx * 4;

    float acc[4][4] = {};

    const int aRow = tid >> 2;        // 0..63
    const int aK   = (tid & 3) * 4;   // 0,4,8,12

    for (int k0 = 0; k0 < K; k0 += BK) {
        // A tile: 64(m) x 16(k), float4 along k
        {
            const float4 av = *reinterpret_cast<const float4*>(
                &A[(long)(by * TILE + aRow) * lda + k0 + aK]);
            As[aRow][aK + 0] = av.x;
            As[aRow][aK + 1] = av.y;
            As[aRow][aK + 2] = av.z;
            As[aRow][aK + 3] = av.w;
        }
        if (!TRANSB) {
            // B tile: 16(k) x 64(n), float4 along n
            const int bK = tid >> 4;          // 0..15
            const int bC = (tid & 15) * 4;    // 0..60
            const float4 bv = *reinterpret_cast<const float4*>(
                &B[(long)(k0 + bK) * ldb + bx * TILE + bC]);
            *reinterpret_cast<float4*>(&Bs[bK][bC]) = bv;
        } else {
            // B is N x K row-major; need Bs[k][n]
            const int bN = tid >> 2;          // 0..63
            const int bK = (tid & 3) * 4;     // 0,4,8,12
            const float4 bv = *reinterpret_cast<const float4*>(
                &B[(long)(bx * TILE + bN) * ldb + k0 + bK]);
            Bs[bK + 0][bN] = bv.x;
            Bs[bK + 1][bN] = bv.y;
            Bs[bK + 2][bN] = bv.z;
            Bs[bK + 3][bN] = bv.w;
        }
        __syncthreads();

        #pragma unroll
        for (int k = 0; k < BK; ++k) {
            float a[4], b[4];
            #pragma unroll
            for (int i = 0; i < 4; ++i) a[i] = As[ty * 4 + i][k];
            #pragma unroll
            for (int j = 0; j < 4; ++j) b[j] = Bs[k][tx * 4 + j];
            #pragma unroll
            for (int i = 0; i < 4; ++i)
                #pragma unroll
                for (int j = 0; j < 4; ++j)
                    acc[i][j] = fmaf(a[i], b[j], acc[i][j]);
        }
        __syncthreads();
    }

    if (!SPLIT_QK) {
        #pragma unroll
        for (int i = 0; i < 4; ++i) {
            float4 v;
            v.x = alpha * acc[i][0] + (bias ? bias[col0 + 0] : 0.f);
            v.y = alpha * acc[i][1] + (bias ? bias[col0 + 1] : 0.f);
            v.z = alpha * acc[i][2] + (bias ? bias[col0 + 2] : 0.f);
            v.w = alpha * acc[i][3] + (bias ? bias[col0 + 3] : 0.f);
            *reinterpret_cast<float4*>(&C[(long)(row0 + i) * ldc + col0]) = v;
        }
    } else {
        // qk deinterleave: even col -> Q (C), odd col -> K (C2); ld = 320
        #pragma unroll
        for (int i = 0; i < 4; ++i) {
            #pragma unroll
            for (int j = 0; j < 4; ++j) {
                const int c = col0 + j;
                const float v = acc[i][j] + bias[c];
                float* dst = (c & 1) ? C2 : C;
                dst[(long)(row0 + i) * 320 + (c >> 1)] = v;
            }
        }
    }
}

// ---------------------------------------------------------------------------
// Exact k-th-largest (k=171) per row of 1024 via 4-pass radix select on
// order-preserving float->uint keys, then masked softmax. One block (256
// threads, 4 elems/thread) per row.
// ---------------------------------------------------------------------------
__global__ __launch_bounds__(256) void topk_softmax(float* __restrict__ at)
{
    __shared__ int hist[256];
    __shared__ unsigned bcastDigit;
    __shared__ int bcastK;
    __shared__ float redMax[4];
    __shared__ float redSum[4];

    const int tid  = threadIdx.x;
    const int lane = tid & 63;
    const int wave = tid >> 6;
    float* row = at + (long)blockIdx.x * 1024;

    // load 4 contiguous elements (float4, fully coalesced)
    float4 v4 = reinterpret_cast<const float4*>(row)[tid];
    float v[4] = {v4.x, v4.y, v4.z, v4.w};

    // order-preserving map: ascending uint keys
    unsigned key[4];
    #pragma unroll
    for (int i = 0; i < 4; ++i) {
        unsigned u = __float_as_uint(v[i]);
        key[i] = (u & 0x80000000u) ? ~u : (u | 0x80000000u);
    }

    unsigned prefix = 0;   // selected high bits of the k-th largest key
    unsigned pmask  = 0;   // which bits of prefix are valid
    int kk = 171;          // rank among candidates (1-indexed, from the top)

    #pragma unroll
    for (int pass = 0; pass < 4; ++pass) {
        const int shift = 24 - 8 * pass;
        hist[tid] = 0;
        __syncthreads();
        #pragma unroll
        for (int i = 0; i < 4; ++i) {
            if ((key[i] & pmask) == prefix)
                atomicAdd(&hist[(key[i] >> shift) & 255], 1);
        }
        __syncthreads();
        if (wave == 0) {
            // lane l owns bins 4l..4l+3; suffix-sum from the top across lanes
            const int h0 = hist[4 * lane + 0];
            const int h1 = hist[4 * lane + 1];
            const int h2 = hist[4 * lane + 2];
            const int h3 = hist[4 * lane + 3];
            const int s = h0 + h1 + h2 + h3;
            int suf = s;  // inclusive suffix sum over lanes >= l
            #pragma unroll
            for (int off = 1; off < 64; off <<= 1) {
                const int o = __shfl_down(suf, off);
                if (lane + off < 64) suf += o;
            }
            const int above = suf - s;       // candidates in higher lanes
            const int cgt3 = above;          // cnt of candidates with digit > d
            const int cgt2 = cgt3 + h3;
            const int cgt1 = cgt2 + h2;
            const int cgt0 = cgt1 + h1;
            if (cgt3 < kk && kk <= cgt3 + h3) { bcastDigit = 4 * lane + 3; bcastK = kk - cgt3; }
            if (cgt2 < kk && kk <= cgt2 + h2) { bcastDigit = 4 * lane + 2; bcastK = kk - cgt2; }
            if (cgt1 < kk && kk <= cgt1 + h1) { bcastDigit = 4 * lane + 1; bcastK = kk - cgt1; }
            if (cgt0 < kk && kk <= cgt0 + h0) { bcastDigit = 4 * lane + 0; bcastK = kk - cgt0; }
        }
        __syncthreads();
        prefix |= (bcastDigit << shift);
        pmask  |= (0xFFu << shift);
        kk = bcastK;
        // no barrier needed: next write to bcast* is 2 barriers away
    }

    // exact threshold value (the 171st largest)
    const float thr = (prefix & 0x80000000u)
                          ? __uint_as_float(prefix & 0x7FFFFFFFu)
                          : __uint_as_float(~prefix);

    // masked logits + row max
    float lg[4];
    float mx = -3.4e38f;
    #pragma unroll
    for (int i = 0; i < 4; ++i) {
        const float a = (v[i] < thr) ? -1e-7f : v[i];
        lg[i] = a * (1.0f / 0.3f);
        mx = fmaxf(mx, lg[i]);
    }
    #pragma unroll
    for (int off = 32; off > 0; off >>= 1) mx = fmaxf(mx, __shfl_xor(mx, off));
    if (lane == 0) redMax[wave] = mx;
    __syncthreads();
    mx = fmaxf(fmaxf(redMax[0], redMax[1]), fmaxf(redMax[2], redMax[3]));

    float e[4];
    float sum = 0.f;
    #pragma unroll
    for (int i = 0; i < 4; ++i) { e[i] = __expf(lg[i] - mx); sum += e[i]; }
    #pragma unroll
    for (int off = 32; off > 0; off >>= 1) sum += __shfl_xor(sum, off);
    if (lane == 0) redSum[wave] = sum;
    __syncthreads();
    sum = (redSum[0] + redSum[1]) + (redSum[2] + redSum[3]);

    const float inv = 1.0f / sum;
    float4 o;
    o.x = e[0] * inv; o.y = e[1] * inv; o.z = e[2] * inv; o.w = e[3] * inv;
    reinterpret_cast<float4*>(row)[tid] = o;
}

extern "C" void kernel_launch(void* const* d_in, const int* in_sizes, int n_in,
                              void* d_out, int out_size, void* d_ws, size_t ws_size,
                              hipStream_t stream) {
    (void)in_sizes; (void)n_in; (void)out_size; (void)ws_size;

    const float* h      = (const float*)d_in[0];  // 8x1024x320
    const float* Wqk    = (const float*)d_in[1];  // 320x640
    const float* bqk    = (const float*)d_in[2];  // 640
    const float* weight = (const float*)d_in[3];  // 320x320
    const float* bias   = (const float*)d_in[4];  // 320
    float* out = (float*)d_out;                   // 8x1024x320

    float* Q    = (float*)d_ws;          // 8192*320
    float* Kb   = Q  + 2621440;          // 8192*320
    float* at   = Kb + 2621440;          // 8*1024*1024
    float* of   = at + 8388608;          // 8192*320

    const dim3 blk(16, 16);

    // 1) qk = h @ Wqk + bqk, split -> Q,K   (M=8192,N=640,K=320)
    gemm64<false, true, 0><<<dim3(640 / TILE, 8192 / TILE, 1), blk, 0, stream>>>(
        h, Wqk, Q, Kb, bqk, 8192, 640, 320, 320, 640, 320, 0, 0, 0, 1.0f);

    // 2) at = 0.125 * Q @ K^T per batch    (M=1024,N=1024,K=320)
    gemm64<true, false, 1><<<dim3(1024 / TILE, 1024 / TILE, 8), blk, 0, stream>>>(
        Q, Kb, at, nullptr, nullptr, 1024, 1024, 320, 320, 320, 1024,
        327680, 327680, 1048576, 0.125f);

    // 3) threshold + softmax in place (radix select)
    topk_softmax<<<8192, 256, 0, stream>>>(at);

    // 4) of = attn @ h per batch           (M=1024,N=320,K=1024)
    gemm64<false, false, 0><<<dim3(320 / TILE, 1024 / TILE, 8), blk, 0, stream>>>(
        at, h, of, nullptr, nullptr, 1024, 320, 1024, 1024, 320, 320,
        1048576, 327680, 327680, 1.0f);

    // 5) out = of @ weight + bias          (M=8192,N=320,K=320)
    gemm64<false, false, 0><<<dim3(320 / TILE, 8192 / TILE, 1), blk, 0, stream>>>(
        of, weight, out, nullptr, bias, 8192, 320, 320, 320, 320, 320,
        0, 0, 0, 1.0f);
}

// Round 3
// 204.466 us; speedup vs baseline: 2.9863x; 1.8782x over previous
//
#include <hip/hip_runtime.h>

// ---------------------------------------------------------------------------
// B=8, N=1024, F=320, H=5 (heads collapse: at = (Q·K^T)/8)
// R2: all GEMMs -> bf16 MFMA (16x16x32), NT form.
//   QK^T chain (GEMM1, GEMM2) uses bf16x3 split (hi*hi + hi*lo + lo*hi).
//   Post-softmax chain (GEMM4, GEMM5) uses plain bf16.
// Pipeline:
//   prep: split h -> (h_hi,h_lo); transpose h -> hT(bf16); transpose+split Wqk;
//         transpose weight -> wT(bf16)
//   G1: [h_hi,h_lo] @ [WqkT_hi,WqkT_lo]^T + bqk -> deinterleave -> Q_hi/lo, K_hi/lo
//   G2: at = 0.125 * [Q]@[K]^T  (fp32 out)
//   topk_softmax: exact radix select + softmax, writes attn (bf16)
//   G4: of = attn @ hT^T (bf16 out)
//   G5: out = of @ wT^T + bias (fp32 out)
// ---------------------------------------------------------------------------

typedef __attribute__((ext_vector_type(8))) short short8;
typedef __attribute__((ext_vector_type(4))) float f32x4;

__device__ __forceinline__ unsigned short f2bf(float f) {
    unsigned u = __float_as_uint(f);
    return (unsigned short)((u + 0x7FFFu + ((u >> 16) & 1u)) >> 16);
}
__device__ __forceinline__ float bf2f(unsigned short s) {
    return __uint_as_float(((unsigned)s) << 16);
}

// ---- stage a (nrow16*16) x 32 bf16 tile (row-major, ld elems) into LDS -----
__device__ __forceinline__ void stage_tile(const unsigned short* g,
                                           unsigned short* lds, int nrow16,
                                           int ld, int wave, int lane) {
    const int r = lane >> 2;
    const int c = (lane & 3) * 8;
    for (int i = wave; i < nrow16; i += 4) {
        const unsigned short* src = g + (long)(i * 16 + r) * ld + c;
        __builtin_amdgcn_global_load_lds(
            (const __attribute__((address_space(1))) unsigned int*)src,
            (__attribute__((address_space(3))) unsigned int*)(lds + i * 512),
            16, 0, 0);
    }
}

// ---------------------------------------------------------------------------
// NT MFMA GEMM: C[m][n] = alpha * sum_k A[m][k]*B[n][k] (+epilogue)
// BM=128, BN=64, BK=32; 256 threads = 4 waves in 2x2 grid (64x32 per wave).
// EPI: 0 = fp32 store (alpha)          [GEMM2 -> at]
//      1 = +bqk, deinterleave Q/K, split hi/lo bf16 stores  [GEMM1]
//      2 = bf16 store                   [GEMM4 -> of]
//      3 = fp32 store + bias            [GEMM5 -> out]
// ---------------------------------------------------------------------------
template <bool SPLIT, int EPI>
__global__ __launch_bounds__(256) void gemm_nt(
    const unsigned short* __restrict__ Ahi, const unsigned short* __restrict__ Alo,
    const unsigned short* __restrict__ Bhi, const unsigned short* __restrict__ Blo,
    void* __restrict__ C, void* __restrict__ C2,
    void* __restrict__ C3, void* __restrict__ C4,
    const float* __restrict__ bias,
    int K, int lda, int ldb, int ldc,
    long sA, long sB, long sC, float alpha)
{
    constexpr int A_EL = 128 * 32;  // 4096 shorts
    constexpr int B_EL = 64 * 32;   // 2048 shorts
    __shared__ unsigned short smem[SPLIT ? (2 * A_EL + 2 * B_EL) : (A_EL + B_EL)];
    unsigned short* sAh = smem;
    unsigned short* sAl = SPLIT ? smem + A_EL : smem;
    unsigned short* sBh = smem + (SPLIT ? 2 * A_EL : A_EL);
    unsigned short* sBl = SPLIT ? sBh + B_EL : sBh;

    const int tid  = threadIdx.x;
    const int lane = tid & 63;
    const int wave = tid >> 6;
    const int wm   = wave >> 1;   // 0..1
    const int wn   = wave & 1;    // 0..1
    const int bz   = blockIdx.z;

    const unsigned short* Ab_hi = Ahi + bz * sA + (long)blockIdx.y * 128 * lda;
    const unsigned short* Bb_hi = Bhi + bz * sB + (long)blockIdx.x * 64 * ldb;
    const unsigned short* Ab_lo = SPLIT ? Alo + bz * sA + (long)blockIdx.y * 128 * lda : nullptr;
    const unsigned short* Bb_lo = SPLIT ? Blo + bz * sB + (long)blockIdx.x * 64 * ldb : nullptr;

    f32x4 acc[4][2];
    #pragma unroll
    for (int i = 0; i < 4; ++i)
        #pragma unroll
        for (int j = 0; j < 2; ++j) acc[i][j] = (f32x4){0.f, 0.f, 0.f, 0.f};

    const int lrow = lane & 15;
    const int quad = lane >> 4;

    for (int k0 = 0; k0 < K; k0 += 32) {
        stage_tile(Ab_hi + k0, sAh, 8, lda, wave, lane);
        stage_tile(Bb_hi + k0, sBh, 4, ldb, wave, lane);
        if (SPLIT) {
            stage_tile(Ab_lo + k0, sAl, 8, lda, wave, lane);
            stage_tile(Bb_lo + k0, sBl, 4, ldb, wave, lane);
        }
        __syncthreads();

        short8 ah[4], bh[2], al[4], bl[2];
        const unsigned short* pA = sAh + (wm * 64 + lrow) * 32 + quad * 8;
        const unsigned short* pB = sBh + (wn * 32 + lrow) * 32 + quad * 8;
        #pragma unroll
        for (int mt = 0; mt < 4; ++mt) ah[mt] = *(const short8*)(pA + mt * 512);
        #pragma unroll
        for (int nt = 0; nt < 2; ++nt) bh[nt] = *(const short8*)(pB + nt * 512);
        if (SPLIT) {
            const unsigned short* qA = sAl + (wm * 64 + lrow) * 32 + quad * 8;
            const unsigned short* qB = sBl + (wn * 32 + lrow) * 32 + quad * 8;
            #pragma unroll
            for (int mt = 0; mt < 4; ++mt) al[mt] = *(const short8*)(qA + mt * 512);
            #pragma unroll
            for (int nt = 0; nt < 2; ++nt) bl[nt] = *(const short8*)(qB + nt * 512);
        }

        #pragma unroll
        for (int mt = 0; mt < 4; ++mt)
            #pragma unroll
            for (int nt = 0; nt < 2; ++nt) {
                acc[mt][nt] = __builtin_amdgcn_mfma_f32_16x16x32_bf16(
                    ah[mt], bh[nt], acc[mt][nt], 0, 0, 0);
                if (SPLIT) {
                    acc[mt][nt] = __builtin_amdgcn_mfma_f32_16x16x32_bf16(
                        ah[mt], bl[nt], acc[mt][nt], 0, 0, 0);
                    acc[mt][nt] = __builtin_amdgcn_mfma_f32_16x16x32_bf16(
                        al[mt], bh[nt], acc[mt][nt], 0, 0, 0);
                }
            }
        __syncthreads();
    }

    // epilogue: C[row][col]; col = lane&15 within tile, row = quad*4 + r
    const int row_base = blockIdx.y * 128 + wm * 64;
    const int col_base = blockIdx.x * 64 + wn * 32;
    #pragma unroll
    for (int mt = 0; mt < 4; ++mt)
        #pragma unroll
        for (int nt = 0; nt < 2; ++nt)
            #pragma unroll
            for (int r = 0; r < 4; ++r) {
                const int row = row_base + mt * 16 + quad * 4 + r;
                const int col = col_base + nt * 16 + lrow;
                const float v = acc[mt][nt][r];
                if (EPI == 0) {
                    ((float*)C)[bz * sC + (long)row * ldc + col] = alpha * v;
                } else if (EPI == 1) {
                    const float val = v + bias[col];
                    const unsigned short hi = f2bf(val);
                    const unsigned short lo = f2bf(val - bf2f(hi));
                    const long idx = (long)row * 320 + (col >> 1);
                    if (col & 1) {
                        ((unsigned short*)C3)[idx] = hi;
                        ((unsigned short*)C4)[idx] = lo;
                    } else {
                        ((unsigned short*)C)[idx]  = hi;
                        ((unsigned short*)C2)[idx] = lo;
                    }
                } else if (EPI == 2) {
                    ((unsigned short*)C)[bz * sC + (long)row * ldc + col] = f2bf(v);
                } else {
                    ((float*)C)[(long)row * ldc + col] = v + bias[col];
                }
            }
}

// ---- elementwise split: fp32 -> bf16 hi + bf16 lo --------------------------
__global__ __launch_bounds__(256) void split2(const float4* __restrict__ src,
                                              ushort4* __restrict__ hi,
                                              ushort4* __restrict__ lo)
{
    const int i = blockIdx.x * 256 + threadIdx.x;
    const float4 v = src[i];
    ushort4 h4, l4;
    h4.x = f2bf(v.x); l4.x = f2bf(v.x - bf2f(h4.x));
    h4.y = f2bf(v.y); l4.y = f2bf(v.y - bf2f(h4.y));
    h4.z = f2bf(v.z); l4.z = f2bf(v.z - bf2f(h4.z));
    h4.w = f2bf(v.w); l4.w = f2bf(v.w - bf2f(h4.w));
    hi[i] = h4; lo[i] = l4;
}

// ---- 32x32 tiled transpose fp32 -> bf16 (optionally split hi/lo) -----------
// src: [.][ldS] tile at rows r0=by*32, cols c0=bx*32 ; dst: [ldS-dim][ldT]
template <bool SPLIT>
__global__ __launch_bounds__(256) void transpose_split(
    const float* __restrict__ src, unsigned short* __restrict__ dhi,
    unsigned short* __restrict__ dlo, int ldS, int ldT, long sS, long sD)
{
    __shared__ float t[32][33];
    const int c0 = blockIdx.x * 32, r0 = blockIdx.y * 32;
    const int lx = threadIdx.x & 31, ly = threadIdx.x >> 5;  // ly: 0..7
    src += blockIdx.z * sS;
    #pragma unroll
    for (int i = 0; i < 4; ++i)
        t[ly + 8 * i][lx] = src[(long)(r0 + ly + 8 * i) * ldS + c0 + lx];
    __syncthreads();
    #pragma unroll
    for (int i = 0; i < 4; ++i) {
        const float v = t[lx][ly + 8 * i];
        const long o = blockIdx.z * sD + (long)(c0 + ly + 8 * i) * ldT + r0 + lx;
        const unsigned short h = f2bf(v);
        dhi[o] = h;
        if (SPLIT) dlo[o] = f2bf(v - bf2f(h));
    }
}

// ---------------------------------------------------------------------------
// Exact k-th-largest (k=171) per row of 1024 via 4-pass radix select,
// then masked softmax. Reads fp32 `at`, writes bf16 `attn`.
// ---------------------------------------------------------------------------
__global__ __launch_bounds__(256) void topk_softmax(const float* __restrict__ at,
                                                    unsigned short* __restrict__ attn)
{
    __shared__ int hist[256];
    __shared__ unsigned bcastDigit;
    __shared__ int bcastK;
    __shared__ float redMax[4];
    __shared__ float redSum[4];

    const int tid  = threadIdx.x;
    const int lane = tid & 63;
    const int wave = tid >> 6;
    const float* row = at + (long)blockIdx.x * 1024;

    float4 v4 = reinterpret_cast<const float4*>(row)[tid];
    float v[4] = {v4.x, v4.y, v4.z, v4.w};

    unsigned key[4];
    #pragma unroll
    for (int i = 0; i < 4; ++i) {
        unsigned u = __float_as_uint(v[i]);
        key[i] = (u & 0x80000000u) ? ~u : (u | 0x80000000u);
    }

    unsigned prefix = 0, pmask = 0;
    int kk = 171;

    #pragma unroll
    for (int pass = 0; pass < 4; ++pass) {
        const int shift = 24 - 8 * pass;
        hist[tid] = 0;
        __syncthreads();
        #pragma unroll
        for (int i = 0; i < 4; ++i) {
            if ((key[i] & pmask) == prefix)
                atomicAdd(&hist[(key[i] >> shift) & 255], 1);
        }
        __syncthreads();
        if (wave == 0) {
            const int h0 = hist[4 * lane + 0];
            const int h1 = hist[4 * lane + 1];
            const int h2 = hist[4 * lane + 2];
            const int h3 = hist[4 * lane + 3];
            const int s = h0 + h1 + h2 + h3;
            int suf = s;
            #pragma unroll
            for (int off = 1; off < 64; off <<= 1) {
                const int o = __shfl_down(suf, off);
                if (lane + off < 64) suf += o;
            }
            const int cgt3 = suf - s;
            const int cgt2 = cgt3 + h3;
            const int cgt1 = cgt2 + h2;
            const int cgt0 = cgt1 + h1;
            if (cgt3 < kk && kk <= cgt3 + h3) { bcastDigit = 4 * lane + 3; bcastK = kk - cgt3; }
            if (cgt2 < kk && kk <= cgt2 + h2) { bcastDigit = 4 * lane + 2; bcastK = kk - cgt2; }
            if (cgt1 < kk && kk <= cgt1 + h1) { bcastDigit = 4 * lane + 1; bcastK = kk - cgt1; }
            if (cgt0 < kk && kk <= cgt0 + h0) { bcastDigit = 4 * lane + 0; bcastK = kk - cgt0; }
        }
        __syncthreads();
        prefix |= (bcastDigit << shift);
        pmask  |= (0xFFu << shift);
        kk = bcastK;
    }

    const float thr = (prefix & 0x80000000u)
                          ? __uint_as_float(prefix & 0x7FFFFFFFu)
                          : __uint_as_float(~prefix);

    float lg[4];
    float mx = -3.4e38f;
    #pragma unroll
    for (int i = 0; i < 4; ++i) {
        const float a = (v[i] < thr) ? -1e-7f : v[i];
        lg[i] = a * (1.0f / 0.3f);
        mx = fmaxf(mx, lg[i]);
    }
    #pragma unroll
    for (int off = 32; off > 0; off >>= 1) mx = fmaxf(mx, __shfl_xor(mx, off));
    if (lane == 0) redMax[wave] = mx;
    __syncthreads();
    mx = fmaxf(fmaxf(redMax[0], redMax[1]), fmaxf(redMax[2], redMax[3]));

    float e[4];
    float sum = 0.f;
    #pragma unroll
    for (int i = 0; i < 4; ++i) { e[i] = __expf(lg[i] - mx); sum += e[i]; }
    #pragma unroll
    for (int off = 32; off > 0; off >>= 1) sum += __shfl_xor(sum, off);
    if (lane == 0) redSum[wave] = sum;
    __syncthreads();
    sum = (redSum[0] + redSum[1]) + (redSum[2] + redSum[3]);

    const float inv = 1.0f / sum;
    ushort4 o;
    o.x = f2bf(e[0] * inv); o.y = f2bf(e[1] * inv);
    o.z = f2bf(e[2] * inv); o.w = f2bf(e[3] * inv);
    reinterpret_cast<ushort4*>(attn + (long)blockIdx.x * 1024)[tid] = o;
}

extern "C" void kernel_launch(void* const* d_in, const int* in_sizes, int n_in,
                              void* d_out, int out_size, void* d_ws, size_t ws_size,
                              hipStream_t stream) {
    (void)in_sizes; (void)n_in; (void)out_size; (void)ws_size;

    const float* h      = (const float*)d_in[0];  // 8x1024x320
    const float* Wqk    = (const float*)d_in[1];  // 320x640
    const float* bqk    = (const float*)d_in[2];  // 640
    const float* weight = (const float*)d_in[3];  // 320x320
    const float* bias   = (const float*)d_in[4];  // 320
    float* out = (float*)d_out;                   // 8192x320

    // workspace layout (bytes)
    char* p = (char*)d_ws;
    float*          at      = (float*)p;          p += 8L * 1024 * 1024 * 4;   // 32 MB
    unsigned short* attn    = (unsigned short*)p; p += 8192L * 1024 * 2;       // 16 MB
    unsigned short* h_hi    = (unsigned short*)p; p += 2621440L * 2;
    unsigned short* h_lo    = (unsigned short*)p; p += 2621440L * 2;
    unsigned short* hT      = (unsigned short*)p; p += 2621440L * 2;
    unsigned short* Qhi     = (unsigned short*)p; p += 2621440L * 2;
    unsigned short* Qlo     = (unsigned short*)p; p += 2621440L * 2;
    unsigned short* Khi     = (unsigned short*)p; p += 2621440L * 2;
    unsigned short* Klo     = (unsigned short*)p; p += 2621440L * 2;
    unsigned short* WqkThi  = (unsigned short*)p; p += 204800L * 2;
    unsigned short* WqkTlo  = (unsigned short*)p; p += 204800L * 2;
    unsigned short* wT      = (unsigned short*)p; p += 102400L * 2;
    unsigned short* of      = (unsigned short*)p; p += 2621440L * 2;

    // --- prep ---
    split2<<<2560, 256, 0, stream>>>((const float4*)h, (ushort4*)h_hi, (ushort4*)h_lo);
    transpose_split<false><<<dim3(10, 32, 8), 256, 0, stream>>>(
        h, hT, nullptr, 320, 1024, 327680, 327680);
    transpose_split<true><<<dim3(20, 10, 1), 256, 0, stream>>>(
        Wqk, WqkThi, WqkTlo, 640, 320, 0, 0);
    transpose_split<false><<<dim3(10, 10, 1), 256, 0, stream>>>(
        weight, wT, nullptr, 320, 320, 0, 0);

    // --- G1: qk = h@Wqk + bqk -> Q/K hi/lo (split bf16x3) ---
    gemm_nt<true, 1><<<dim3(10, 64, 1), 256, 0, stream>>>(
        h_hi, h_lo, WqkThi, WqkTlo, Qhi, Qlo, Khi, Klo, bqk,
        320, 320, 320, 320, 0, 0, 0, 1.0f);

    // --- G2: at = 0.125 * Q@K^T (split bf16x3, fp32 out) ---
    gemm_nt<true, 0><<<dim3(16, 8, 8), 256, 0, stream>>>(
        Qhi, Qlo, Khi, Klo, at, nullptr, nullptr, nullptr, nullptr,
        320, 320, 320, 1024, 327680, 327680, 1048576, 0.125f);

    // --- topk + softmax -> attn (bf16) ---
    topk_softmax<<<8192, 256, 0, stream>>>(at, attn);

    // --- G4: of = attn @ h (bf16, bf16 out) ---
    gemm_nt<false, 2><<<dim3(5, 8, 8), 256, 0, stream>>>(
        attn, nullptr, hT, nullptr, of, nullptr, nullptr, nullptr, nullptr,
        1024, 1024, 1024, 320, 1048576, 327680, 327680, 1.0f);

    // --- G5: out = of @ weight + bias (bf16, fp32 out) ---
    gemm_nt<false, 3><<<dim3(5, 64, 1), 256, 0, stream>>>(
        of, nullptr, wT, nullptr, out, nullptr, nullptr, nullptr, bias,
        320, 320, 320, 320, 0, 0, 0, 1.0f);
}

// Round 4
// 182.604 us; speedup vs baseline: 3.3438x; 1.1197x over previous
//
#include <hip/hip_runtime.h>
#include <hip/hip_fp16.h>

// ---------------------------------------------------------------------------
// B=8, N=1024, F=320, H=5 (heads collapse: at = (Q·K^T)/8)
// R3: at stored as fp16 (16-bit keys -> 2-pass exact radix select),
//     wave-per-row topk_softmax (4 rows/block, shuffle broadcast),
//     fused h prep (split hi/lo + transpose in one pass).
// Pipeline:
//   prep_h: h -> h_hi,h_lo (bf16) + hT (bf16)
//   transpose Wqk (split), transpose weight
//   G1: [h_hi,h_lo]@[WqkT]^T + bqk -> Q_hi/lo, K_hi/lo   (bf16x3)
//   G2: at = 0.125 * Q@K^T  -> fp16                      (bf16x3)
//   topk_softmax: exact 171st-largest + softmax -> attn (bf16)
//   G4: of = attn @ hT^T (bf16)
//   G5: out = of @ wT^T + bias (fp32)
// ---------------------------------------------------------------------------

typedef __attribute__((ext_vector_type(8))) short short8;
typedef __attribute__((ext_vector_type(4))) float f32x4;

__device__ __forceinline__ unsigned short f2bf(float f) {
    unsigned u = __float_as_uint(f);
    return (unsigned short)((u + 0x7FFFu + ((u >> 16) & 1u)) >> 16);
}
__device__ __forceinline__ float bf2f(unsigned short s) {
    return __uint_as_float(((unsigned)s) << 16);
}

// ---- stage a (nrow16*16) x 32 bf16 tile (row-major, ld elems) into LDS -----
__device__ __forceinline__ void stage_tile(const unsigned short* g,
                                           unsigned short* lds, int nrow16,
                                           int ld, int wave, int lane) {
    const int r = lane >> 2;
    const int c = (lane & 3) * 8;
    for (int i = wave; i < nrow16; i += 4) {
        const unsigned short* src = g + (long)(i * 16 + r) * ld + c;
        __builtin_amdgcn_global_load_lds(
            (const __attribute__((address_space(1))) unsigned int*)src,
            (__attribute__((address_space(3))) unsigned int*)(lds + i * 512),
            16, 0, 0);
    }
}

// ---------------------------------------------------------------------------
// NT MFMA GEMM: C[m][n] = alpha * sum_k A[m][k]*B[n][k] (+epilogue)
// BM=128, BN=64, BK=32; 256 threads = 4 waves in 2x2 grid (64x32 per wave).
// EPI: 1 = +bqk, deinterleave Q/K, split hi/lo bf16 stores  [GEMM1]
//      2 = bf16 store                   [GEMM4 -> of]
//      3 = fp32 store + bias            [GEMM5 -> out]
//      4 = fp16 store (alpha)           [GEMM2 -> at]
// ---------------------------------------------------------------------------
template <bool SPLIT, int EPI>
__global__ __launch_bounds__(256) void gemm_nt(
    const unsigned short* __restrict__ Ahi, const unsigned short* __restrict__ Alo,
    const unsigned short* __restrict__ Bhi, const unsigned short* __restrict__ Blo,
    void* __restrict__ C, void* __restrict__ C2,
    void* __restrict__ C3, void* __restrict__ C4,
    const float* __restrict__ bias,
    int K, int lda, int ldb, int ldc,
    long sA, long sB, long sC, float alpha)
{
    constexpr int A_EL = 128 * 32;  // 4096 shorts
    constexpr int B_EL = 64 * 32;   // 2048 shorts
    __shared__ unsigned short smem[SPLIT ? (2 * A_EL + 2 * B_EL) : (A_EL + B_EL)];
    unsigned short* sAh = smem;
    unsigned short* sAl = SPLIT ? smem + A_EL : smem;
    unsigned short* sBh = smem + (SPLIT ? 2 * A_EL : A_EL);
    unsigned short* sBl = SPLIT ? sBh + B_EL : sBh;

    const int tid  = threadIdx.x;
    const int lane = tid & 63;
    const int wave = tid >> 6;
    const int wm   = wave >> 1;   // 0..1
    const int wn   = wave & 1;    // 0..1
    const int bz   = blockIdx.z;

    const unsigned short* Ab_hi = Ahi + bz * sA + (long)blockIdx.y * 128 * lda;
    const unsigned short* Bb_hi = Bhi + bz * sB + (long)blockIdx.x * 64 * ldb;
    const unsigned short* Ab_lo = SPLIT ? Alo + bz * sA + (long)blockIdx.y * 128 * lda : nullptr;
    const unsigned short* Bb_lo = SPLIT ? Blo + bz * sB + (long)blockIdx.x * 64 * ldb : nullptr;

    f32x4 acc[4][2];
    #pragma unroll
    for (int i = 0; i < 4; ++i)
        #pragma unroll
        for (int j = 0; j < 2; ++j) acc[i][j] = (f32x4){0.f, 0.f, 0.f, 0.f};

    const int lrow = lane & 15;
    const int quad = lane >> 4;

    for (int k0 = 0; k0 < K; k0 += 32) {
        stage_tile(Ab_hi + k0, sAh, 8, lda, wave, lane);
        stage_tile(Bb_hi + k0, sBh, 4, ldb, wave, lane);
        if (SPLIT) {
            stage_tile(Ab_lo + k0, sAl, 8, lda, wave, lane);
            stage_tile(Bb_lo + k0, sBl, 4, ldb, wave, lane);
        }
        __syncthreads();

        short8 ah[4], bh[2], al[4], bl[2];
        const unsigned short* pA = sAh + (wm * 64 + lrow) * 32 + quad * 8;
        const unsigned short* pB = sBh + (wn * 32 + lrow) * 32 + quad * 8;
        #pragma unroll
        for (int mt = 0; mt < 4; ++mt) ah[mt] = *(const short8*)(pA + mt * 512);
        #pragma unroll
        for (int nt = 0; nt < 2; ++nt) bh[nt] = *(const short8*)(pB + nt * 512);
        if (SPLIT) {
            const unsigned short* qA = sAl + (wm * 64 + lrow) * 32 + quad * 8;
            const unsigned short* qB = sBl + (wn * 32 + lrow) * 32 + quad * 8;
            #pragma unroll
            for (int mt = 0; mt < 4; ++mt) al[mt] = *(const short8*)(qA + mt * 512);
            #pragma unroll
            for (int nt = 0; nt < 2; ++nt) bl[nt] = *(const short8*)(qB + nt * 512);
        }

        #pragma unroll
        for (int mt = 0; mt < 4; ++mt)
            #pragma unroll
            for (int nt = 0; nt < 2; ++nt) {
                acc[mt][nt] = __builtin_amdgcn_mfma_f32_16x16x32_bf16(
                    ah[mt], bh[nt], acc[mt][nt], 0, 0, 0);
                if (SPLIT) {
                    acc[mt][nt] = __builtin_amdgcn_mfma_f32_16x16x32_bf16(
                        ah[mt], bl[nt], acc[mt][nt], 0, 0, 0);
                    acc[mt][nt] = __builtin_amdgcn_mfma_f32_16x16x32_bf16(
                        al[mt], bh[nt], acc[mt][nt], 0, 0, 0);
                }
            }
        __syncthreads();
    }

    // epilogue: C[row][col]; col = lane&15 within tile, row = quad*4 + r
    const int row_base = blockIdx.y * 128 + wm * 64;
    const int col_base = blockIdx.x * 64 + wn * 32;
    #pragma unroll
    for (int mt = 0; mt < 4; ++mt)
        #pragma unroll
        for (int nt = 0; nt < 2; ++nt)
            #pragma unroll
            for (int r = 0; r < 4; ++r) {
                const int row = row_base + mt * 16 + quad * 4 + r;
                const int col = col_base + nt * 16 + lrow;
                const float v = acc[mt][nt][r];
                if (EPI == 1) {
                    const float val = v + bias[col];
                    const unsigned short hi = f2bf(val);
                    const unsigned short lo = f2bf(val - bf2f(hi));
                    const long idx = (long)row * 320 + (col >> 1);
                    if (col & 1) {
                        ((unsigned short*)C3)[idx] = hi;
                        ((unsigned short*)C4)[idx] = lo;
                    } else {
                        ((unsigned short*)C)[idx]  = hi;
                        ((unsigned short*)C2)[idx] = lo;
                    }
                } else if (EPI == 2) {
                    ((unsigned short*)C)[bz * sC + (long)row * ldc + col] = f2bf(v);
                } else if (EPI == 3) {
                    ((float*)C)[(long)row * ldc + col] = v + bias[col];
                } else {  // EPI == 4
                    ((__half*)C)[bz * sC + (long)row * ldc + col] =
                        __float2half(alpha * v);
                }
            }
}

// ---- fused h prep: h(fp32) -> h_hi,h_lo (bf16, same layout) + hT (bf16) ----
__global__ __launch_bounds__(256) void prep_h(const float* __restrict__ src,
                                              unsigned short* __restrict__ dhi,
                                              unsigned short* __restrict__ dlo,
                                              unsigned short* __restrict__ dT)
{
    __shared__ float t[32][33];
    const int c0 = blockIdx.x * 32, r0 = blockIdx.y * 32;
    const int lx = threadIdx.x & 31, ly = threadIdx.x >> 5;  // ly: 0..7
    const long sOff = (long)blockIdx.z * 327680;
    #pragma unroll
    for (int i = 0; i < 4; ++i) {
        const long o = sOff + (long)(r0 + ly + 8 * i) * 320 + c0 + lx;
        const float v = src[o];
        t[ly + 8 * i][lx] = v;
        const unsigned short h = f2bf(v);
        dhi[o] = h;
        dlo[o] = f2bf(v - bf2f(h));
    }
    __syncthreads();
    #pragma unroll
    for (int i = 0; i < 4; ++i) {
        const float v = t[lx][ly + 8 * i];
        dT[sOff + (long)(c0 + ly + 8 * i) * 1024 + r0 + lx] = f2bf(v);
    }
}

// ---- 32x32 tiled transpose fp32 -> bf16 (optionally split hi/lo) -----------
template <bool SPLIT>
__global__ __launch_bounds__(256) void transpose_split(
    const float* __restrict__ src, unsigned short* __restrict__ dhi,
    unsigned short* __restrict__ dlo, int ldS, int ldT, long sS, long sD)
{
    __shared__ float t[32][33];
    const int c0 = blockIdx.x * 32, r0 = blockIdx.y * 32;
    const int lx = threadIdx.x & 31, ly = threadIdx.x >> 5;
    src += blockIdx.z * sS;
    #pragma unroll
    for (int i = 0; i < 4; ++i)
        t[ly + 8 * i][lx] = src[(long)(r0 + ly + 8 * i) * ldS + c0 + lx];
    __syncthreads();
    #pragma unroll
    for (int i = 0; i < 4; ++i) {
        const float v = t[lx][ly + 8 * i];
        const long o = blockIdx.z * sD + (long)(c0 + ly + 8 * i) * ldT + r0 + lx;
        const unsigned short h = f2bf(v);
        dhi[o] = h;
        if (SPLIT) dlo[o] = f2bf(v - bf2f(h));
    }
}

// ---------------------------------------------------------------------------
// Exact 171st-largest per row of 1024 fp16 values: 2-pass radix select on
// 16-bit order-preserving keys. One WAVE per row (4 rows / 256-thr block),
// per-wave LDS histograms, shuffle broadcast. Then masked softmax -> bf16.
// ---------------------------------------------------------------------------
__global__ __launch_bounds__(256) void topk_softmax(const __half* __restrict__ at,
                                                    unsigned short* __restrict__ attn)
{
    __shared__ int hist[4][256];
    const int lane = threadIdx.x & 63;
    const int wave = threadIdx.x >> 6;
    const long row = (long)blockIdx.x * 4 + wave;

    // load 16 contiguous fp16 per lane (2x 16B)
    unsigned short vs[16];
    {
        const uint4* p = (const uint4*)(at + row * 1024 + lane * 16);
        *(uint4*)&vs[0] = p[0];
        *(uint4*)&vs[8] = p[1];
    }

    unsigned key[16];
    #pragma unroll
    for (int i = 0; i < 16; ++i) {
        const unsigned u = vs[i];
        key[i] = (u & 0x8000u) ? ((~u) & 0xFFFFu) : (u | 0x8000u);
    }

    unsigned prefix = 0, pmask = 0;
    int kk = 171;

    #pragma unroll
    for (int pass = 0; pass < 2; ++pass) {
        const int shift = 8 - 8 * pass;
        *(int4*)&hist[wave][lane * 4] = make_int4(0, 0, 0, 0);
        __syncthreads();
        #pragma unroll
        for (int i = 0; i < 16; ++i) {
            if ((key[i] & pmask) == prefix)
                atomicAdd(&hist[wave][(key[i] >> shift) & 255], 1);
        }
        __syncthreads();
        const int4 hh = *(const int4*)&hist[wave][lane * 4];
        const int s = hh.x + hh.y + hh.z + hh.w;
        int suf = s;  // inclusive suffix sum over lanes >= lane
        #pragma unroll
        for (int off = 1; off < 64; off <<= 1) {
            const int o = __shfl_down(suf, off);
            if (lane + off < 64) suf += o;
        }
        const int cgt3 = suf - s;
        const int cgt2 = cgt3 + hh.w;
        const int cgt1 = cgt2 + hh.z;
        const int cgt0 = cgt1 + hh.y;
        int pick = 0x7FFFFFFF;
        if (cgt3 < kk && kk <= cgt3 + hh.w) pick = ((4 * lane + 3) << 16) | (kk - cgt3);
        if (cgt2 < kk && kk <= cgt2 + hh.z) pick = ((4 * lane + 2) << 16) | (kk - cgt2);
        if (cgt1 < kk && kk <= cgt1 + hh.y) pick = ((4 * lane + 1) << 16) | (kk - cgt1);
        if (cgt0 < kk && kk <= cgt0 + hh.x) pick = ((4 * lane + 0) << 16) | (kk - cgt0);
        #pragma unroll
        for (int off = 32; off > 0; off >>= 1) pick = min(pick, __shfl_xor(pick, off));
        const unsigned digit = (unsigned)(pick >> 16);
        kk = pick & 0xFFFF;
        prefix |= digit << shift;
        pmask  |= 0xFFu << shift;
        if (pass == 0) __syncthreads();  // WAR on hist before next clear
    }

    // invert key map -> fp16 threshold
    const unsigned short tu = (prefix & 0x8000u) ? (unsigned short)(prefix & 0x7FFFu)
                                                 : (unsigned short)((~prefix) & 0xFFFFu);
    const float thr = __half2float(__ushort_as_half(tu));

    float lg[16];
    float mx = -3.4e38f;
    #pragma unroll
    for (int i = 0; i < 16; ++i) {
        const float v = __half2float(__ushort_as_half(vs[i]));
        const float a = (v < thr) ? -1e-7f : v;
        lg[i] = a * (1.0f / 0.3f);
        mx = fmaxf(mx, lg[i]);
    }
    #pragma unroll
    for (int off = 32; off > 0; off >>= 1) mx = fmaxf(mx, __shfl_xor(mx, off));

    float e[16];
    float sum = 0.f;
    #pragma unroll
    for (int i = 0; i < 16; ++i) { e[i] = __expf(lg[i] - mx); sum += e[i]; }
    #pragma unroll
    for (int off = 32; off > 0; off >>= 1) sum += __shfl_xor(sum, off);
    const float inv = 1.0f / sum;

    unsigned short os[16];
    #pragma unroll
    for (int i = 0; i < 16; ++i) os[i] = f2bf(e[i] * inv);
    uint4* q = (uint4*)(attn + row * 1024 + lane * 16);
    q[0] = *(const uint4*)&os[0];
    q[1] = *(const uint4*)&os[8];
}

extern "C" void kernel_launch(void* const* d_in, const int* in_sizes, int n_in,
                              void* d_out, int out_size, void* d_ws, size_t ws_size,
                              hipStream_t stream) {
    (void)in_sizes; (void)n_in; (void)out_size; (void)ws_size;

    const float* h      = (const float*)d_in[0];  // 8x1024x320
    const float* Wqk    = (const float*)d_in[1];  // 320x640
    const float* bqk    = (const float*)d_in[2];  // 640
    const float* weight = (const float*)d_in[3];  // 320x320
    const float* bias   = (const float*)d_in[4];  // 320
    float* out = (float*)d_out;                   // 8192x320

    // workspace layout
    char* p = (char*)d_ws;
    __half*         at      = (__half*)p;         p += 8388608L * 2;   // 16 MB
    unsigned short* attn    = (unsigned short*)p; p += 8388608L * 2;   // 16 MB
    unsigned short* h_hi    = (unsigned short*)p; p += 2621440L * 2;
    unsigned short* h_lo    = (unsigned short*)p; p += 2621440L * 2;
    unsigned short* hT      = (unsigned short*)p; p += 2621440L * 2;
    unsigned short* Qhi     = (unsigned short*)p; p += 2621440L * 2;
    unsigned short* Qlo     = (unsigned short*)p; p += 2621440L * 2;
    unsigned short* Khi     = (unsigned short*)p; p += 2621440L * 2;
    unsigned short* Klo     = (unsigned short*)p; p += 2621440L * 2;
    unsigned short* WqkThi  = (unsigned short*)p; p += 204800L * 2;
    unsigned short* WqkTlo  = (unsigned short*)p; p += 204800L * 2;
    unsigned short* wT      = (unsigned short*)p; p += 102400L * 2;
    unsigned short* of      = (unsigned short*)p; p += 2621440L * 2;

    // --- prep ---
    prep_h<<<dim3(10, 32, 8), 256, 0, stream>>>(h, h_hi, h_lo, hT);
    transpose_split<true><<<dim3(20, 10, 1), 256, 0, stream>>>(
        Wqk, WqkThi, WqkTlo, 640, 320, 0, 0);
    transpose_split<false><<<dim3(10, 10, 1), 256, 0, stream>>>(
        weight, wT, nullptr, 320, 320, 0, 0);

    // --- G1: qk = h@Wqk + bqk -> Q/K hi/lo (split bf16x3) ---
    gemm_nt<true, 1><<<dim3(10, 64, 1), 256, 0, stream>>>(
        h_hi, h_lo, WqkThi, WqkTlo, Qhi, Qlo, Khi, Klo, bqk,
        320, 320, 320, 320, 0, 0, 0, 1.0f);

    // --- G2: at = 0.125 * Q@K^T (split bf16x3, fp16 out) ---
    gemm_nt<true, 4><<<dim3(16, 8, 8), 256, 0, stream>>>(
        Qhi, Qlo, Khi, Klo, at, nullptr, nullptr, nullptr, nullptr,
        320, 320, 320, 1024, 327680, 327680, 1048576, 0.125f);

    // --- topk + softmax -> attn (bf16); one wave per row ---
    topk_softmax<<<2048, 256, 0, stream>>>(at, attn);

    // --- G4: of = attn @ h (bf16, bf16 out) ---
    gemm_nt<false, 2><<<dim3(5, 8, 8), 256, 0, stream>>>(
        attn, nullptr, hT, nullptr, of, nullptr, nullptr, nullptr, nullptr,
        1024, 1024, 1024, 320, 1048576, 327680, 327680, 1.0f);

    // --- G5: out = of @ weight + bias (bf16, fp32 out) ---
    gemm_nt<false, 3><<<dim3(5, 64, 1), 256, 0, stream>>>(
        of, nullptr, wT, nullptr, out, nullptr, nullptr, nullptr, bias,
        320, 320, 320, 320, 0, 0, 0, 1.0f);
}

// Round 5
// 164.708 us; speedup vs baseline: 3.7071x; 1.1087x over previous
//
#include <hip/hip_runtime.h>
#include <hip/hip_fp16.h>

// ---------------------------------------------------------------------------
// B=8, N=1024, F=320, H=5 (heads collapse: at = (Q·K^T)/8)
// R4: G2 -> plain fp16 MFMA (Q,K stored fp16 by G1's epilogue; fp16 product
//     noise ~= fp16 at-storage quantum already accepted in R3).
//     G4+G5 fused via associativity: out = attn @ (h@weight) + bias;
//     hWT = wT @ h^T computed in prep as bf16 [384pad x 8192].
// Pipeline:
//   split_h: h -> h_hi,h_lo (bf16)
//   transpose Wqk (split hi/lo), transpose weight -> wT
//   hWT GEMM: wT[384pad][320] x h_hi[8192][320] -> hWT bf16 [384][8192]
//   G1 (bf16x3): h@Wqk + bqk -> Q fp16, K fp16
//   G2 (fp16):   at = 0.125 * Q@K^T -> fp16
//   topk_softmax: exact 171st-largest (2-pass radix on 16-bit keys) -> attn bf16
//   G4' (bf16):  out = attn @ hWT^T + bias (fp32)
// ---------------------------------------------------------------------------

typedef __attribute__((ext_vector_type(8))) short short8;
typedef __attribute__((ext_vector_type(8))) _Float16 half8;
typedef __attribute__((ext_vector_type(4))) float f32x4;

__device__ __forceinline__ unsigned short f2bf(float f) {
    unsigned u = __float_as_uint(f);
    return (unsigned short)((u + 0x7FFFu + ((u >> 16) & 1u)) >> 16);
}
__device__ __forceinline__ float bf2f(unsigned short s) {
    return __uint_as_float(((unsigned)s) << 16);
}

// ---- stage a (nrow16*16) x 32 16-bit-elem tile (row-major) into LDS --------
__device__ __forceinline__ void stage_tile(const unsigned short* g,
                                           unsigned short* lds, int nrow16,
                                           int ld, int wave, int lane) {
    const int r = lane >> 2;
    const int c = (lane & 3) * 8;
    for (int i = wave; i < nrow16; i += 4) {
        const unsigned short* src = g + (long)(i * 16 + r) * ld + c;
        __builtin_amdgcn_global_load_lds(
            (const __attribute__((address_space(1))) unsigned int*)src,
            (__attribute__((address_space(3))) unsigned int*)(lds + i * 512),
            16, 0, 0);
    }
}

// ---------------------------------------------------------------------------
// NT MFMA GEMM: C[m][n] = alpha * sum_k A[m][k]*B[n][k] (+epilogue)
// BM=128, BN=64, BK=32; 256 threads = 4 waves (2x2), 64x32 per wave.
// FP16: inputs are fp16, use mfma_f32_16x16x32_f16 (only with SPLIT=false).
// EPI: 1 = +bqk, deinterleave -> Q fp16, K fp16   [G1]
//      2 = bf16 store                              [hWT]
//      3 = fp32 store + bias, batch-strided        [G4' -> out]
//      4 = fp16 store (alpha)                      [G2 -> at]
// ---------------------------------------------------------------------------
template <bool SPLIT, int EPI, bool FP16>
__global__ __launch_bounds__(256) void gemm_nt(
    const unsigned short* __restrict__ Ahi, const unsigned short* __restrict__ Alo,
    const unsigned short* __restrict__ Bhi, const unsigned short* __restrict__ Blo,
    void* __restrict__ C, void* __restrict__ C2,
    const float* __restrict__ bias,
    int K, int lda, int ldb, int ldc,
    long sA, long sB, long sC, float alpha)
{
    constexpr int A_EL = 128 * 32;  // 4096 shorts
    constexpr int B_EL = 64 * 32;   // 2048 shorts
    __shared__ unsigned short smem[SPLIT ? (2 * A_EL + 2 * B_EL) : (A_EL + B_EL)];
    unsigned short* sAh = smem;
    unsigned short* sAl = SPLIT ? smem + A_EL : smem;
    unsigned short* sBh = smem + (SPLIT ? 2 * A_EL : A_EL);
    unsigned short* sBl = SPLIT ? sBh + B_EL : sBh;

    const int tid  = threadIdx.x;
    const int lane = tid & 63;
    const int wave = tid >> 6;
    const int wm   = wave >> 1;   // 0..1
    const int wn   = wave & 1;    // 0..1
    const int bz   = blockIdx.z;

    const unsigned short* Ab_hi = Ahi + bz * sA + (long)blockIdx.y * 128 * lda;
    const unsigned short* Bb_hi = Bhi + bz * sB + (long)blockIdx.x * 64 * ldb;
    const unsigned short* Ab_lo = SPLIT ? Alo + bz * sA + (long)blockIdx.y * 128 * lda : nullptr;
    const unsigned short* Bb_lo = SPLIT ? Blo + bz * sB + (long)blockIdx.x * 64 * ldb : nullptr;

    f32x4 acc[4][2];
    #pragma unroll
    for (int i = 0; i < 4; ++i)
        #pragma unroll
        for (int j = 0; j < 2; ++j) acc[i][j] = (f32x4){0.f, 0.f, 0.f, 0.f};

    const int lrow = lane & 15;
    const int quad = lane >> 4;

    for (int k0 = 0; k0 < K; k0 += 32) {
        stage_tile(Ab_hi + k0, sAh, 8, lda, wave, lane);
        stage_tile(Bb_hi + k0, sBh, 4, ldb, wave, lane);
        if (SPLIT) {
            stage_tile(Ab_lo + k0, sAl, 8, lda, wave, lane);
            stage_tile(Bb_lo + k0, sBl, 4, ldb, wave, lane);
        }
        __syncthreads();

        const unsigned short* pA = sAh + (wm * 64 + lrow) * 32 + quad * 8;
        const unsigned short* pB = sBh + (wn * 32 + lrow) * 32 + quad * 8;

        if (FP16) {
            half8 ah[4], bh[2];
            #pragma unroll
            for (int mt = 0; mt < 4; ++mt) ah[mt] = *(const half8*)(pA + mt * 512);
            #pragma unroll
            for (int nt = 0; nt < 2; ++nt) bh[nt] = *(const half8*)(pB + nt * 512);
            #pragma unroll
            for (int mt = 0; mt < 4; ++mt)
                #pragma unroll
                for (int nt = 0; nt < 2; ++nt)
                    acc[mt][nt] = __builtin_amdgcn_mfma_f32_16x16x32_f16(
                        ah[mt], bh[nt], acc[mt][nt], 0, 0, 0);
        } else {
            short8 ah[4], bh[2], al[4], bl[2];
            #pragma unroll
            for (int mt = 0; mt < 4; ++mt) ah[mt] = *(const short8*)(pA + mt * 512);
            #pragma unroll
            for (int nt = 0; nt < 2; ++nt) bh[nt] = *(const short8*)(pB + nt * 512);
            if (SPLIT) {
                const unsigned short* qA = sAl + (wm * 64 + lrow) * 32 + quad * 8;
                const unsigned short* qB = sBl + (wn * 32 + lrow) * 32 + quad * 8;
                #pragma unroll
                for (int mt = 0; mt < 4; ++mt) al[mt] = *(const short8*)(qA + mt * 512);
                #pragma unroll
                for (int nt = 0; nt < 2; ++nt) bl[nt] = *(const short8*)(qB + nt * 512);
            }
            #pragma unroll
            for (int mt = 0; mt < 4; ++mt)
                #pragma unroll
                for (int nt = 0; nt < 2; ++nt) {
                    acc[mt][nt] = __builtin_amdgcn_mfma_f32_16x16x32_bf16(
                        ah[mt], bh[nt], acc[mt][nt], 0, 0, 0);
                    if (SPLIT) {
                        acc[mt][nt] = __builtin_amdgcn_mfma_f32_16x16x32_bf16(
                            ah[mt], bl[nt], acc[mt][nt], 0, 0, 0);
                        acc[mt][nt] = __builtin_amdgcn_mfma_f32_16x16x32_bf16(
                            al[mt], bh[nt], acc[mt][nt], 0, 0, 0);
                    }
                }
        }
        __syncthreads();
    }

    // epilogue: C[row][col]; col = lane&15 within tile, row = quad*4 + r
    const int row_base = blockIdx.y * 128 + wm * 64;
    const int col_base = blockIdx.x * 64 + wn * 32;
    #pragma unroll
    for (int mt = 0; mt < 4; ++mt)
        #pragma unroll
        for (int nt = 0; nt < 2; ++nt)
            #pragma unroll
            for (int r = 0; r < 4; ++r) {
                const int row = row_base + mt * 16 + quad * 4 + r;
                const int col = col_base + nt * 16 + lrow;
                const float v = acc[mt][nt][r];
                if (EPI == 1) {
                    const float val = v + bias[col];
                    const long idx = (long)row * 320 + (col >> 1);
                    if (col & 1) ((__half*)C2)[idx] = __float2half(val);
                    else         ((__half*)C)[idx]  = __float2half(val);
                } else if (EPI == 2) {
                    ((unsigned short*)C)[bz * sC + (long)row * ldc + col] = f2bf(v);
                } else if (EPI == 3) {
                    ((float*)C)[bz * sC + (long)row * ldc + col] = v + bias[col];
                } else {  // EPI == 4
                    ((__half*)C)[bz * sC + (long)row * ldc + col] =
                        __float2half(alpha * v);
                }
            }
}

// ---- elementwise split: fp32 -> bf16 hi + bf16 lo --------------------------
__global__ __launch_bounds__(256) void split2(const float4* __restrict__ src,
                                              ushort4* __restrict__ hi,
                                              ushort4* __restrict__ lo)
{
    const int i = blockIdx.x * 256 + threadIdx.x;
    const float4 v = src[i];
    ushort4 h4, l4;
    h4.x = f2bf(v.x); l4.x = f2bf(v.x - bf2f(h4.x));
    h4.y = f2bf(v.y); l4.y = f2bf(v.y - bf2f(h4.y));
    h4.z = f2bf(v.z); l4.z = f2bf(v.z - bf2f(h4.z));
    h4.w = f2bf(v.w); l4.w = f2bf(v.w - bf2f(h4.w));
    hi[i] = h4; lo[i] = l4;
}

// ---- 32x32 tiled transpose fp32 -> bf16 (optionally split hi/lo) -----------
template <bool SPLIT>
__global__ __launch_bounds__(256) void transpose_split(
    const float* __restrict__ src, unsigned short* __restrict__ dhi,
    unsigned short* __restrict__ dlo, int ldS, int ldT)
{
    __shared__ float t[32][33];
    const int c0 = blockIdx.x * 32, r0 = blockIdx.y * 32;
    const int lx = threadIdx.x & 31, ly = threadIdx.x >> 5;
    #pragma unroll
    for (int i = 0; i < 4; ++i)
        t[ly + 8 * i][lx] = src[(long)(r0 + ly + 8 * i) * ldS + c0 + lx];
    __syncthreads();
    #pragma unroll
    for (int i = 0; i < 4; ++i) {
        const float v = t[lx][ly + 8 * i];
        const long o = (long)(c0 + ly + 8 * i) * ldT + r0 + lx;
        const unsigned short h = f2bf(v);
        dhi[o] = h;
        if (SPLIT) dlo[o] = f2bf(v - bf2f(h));
    }
}

// ---------------------------------------------------------------------------
// Exact 171st-largest per row of 1024 fp16 values: 2-pass radix select on
// 16-bit order-preserving keys. One wave per row (4 rows / block).
// ---------------------------------------------------------------------------
__global__ __launch_bounds__(256) void topk_softmax(const __half* __restrict__ at,
                                                    unsigned short* __restrict__ attn)
{
    __shared__ int hist[4][256];
    const int lane = threadIdx.x & 63;
    const int wave = threadIdx.x >> 6;
    const long row = (long)blockIdx.x * 4 + wave;

    unsigned short vs[16];
    {
        const uint4* p = (const uint4*)(at + row * 1024 + lane * 16);
        *(uint4*)&vs[0] = p[0];
        *(uint4*)&vs[8] = p[1];
    }

    unsigned key[16];
    #pragma unroll
    for (int i = 0; i < 16; ++i) {
        const unsigned u = vs[i];
        key[i] = (u & 0x8000u) ? ((~u) & 0xFFFFu) : (u | 0x8000u);
    }

    unsigned prefix = 0, pmask = 0;
    int kk = 171;

    #pragma unroll
    for (int pass = 0; pass < 2; ++pass) {
        const int shift = 8 - 8 * pass;
        *(int4*)&hist[wave][lane * 4] = make_int4(0, 0, 0, 0);
        __syncthreads();
        #pragma unroll
        for (int i = 0; i < 16; ++i) {
            if ((key[i] & pmask) == prefix)
                atomicAdd(&hist[wave][(key[i] >> shift) & 255], 1);
        }
        __syncthreads();
        const int4 hh = *(const int4*)&hist[wave][lane * 4];
        const int s = hh.x + hh.y + hh.z + hh.w;
        int suf = s;
        #pragma unroll
        for (int off = 1; off < 64; off <<= 1) {
            const int o = __shfl_down(suf, off);
            if (lane + off < 64) suf += o;
        }
        const int cgt3 = suf - s;
        const int cgt2 = cgt3 + hh.w;
        const int cgt1 = cgt2 + hh.z;
        const int cgt0 = cgt1 + hh.y;
        int pick = 0x7FFFFFFF;
        if (cgt3 < kk && kk <= cgt3 + hh.w) pick = ((4 * lane + 3) << 16) | (kk - cgt3);
        if (cgt2 < kk && kk <= cgt2 + hh.z) pick = ((4 * lane + 2) << 16) | (kk - cgt2);
        if (cgt1 < kk && kk <= cgt1 + hh.y) pick = ((4 * lane + 1) << 16) | (kk - cgt1);
        if (cgt0 < kk && kk <= cgt0 + hh.x) pick = ((4 * lane + 0) << 16) | (kk - cgt0);
        #pragma unroll
        for (int off = 32; off > 0; off >>= 1) pick = min(pick, __shfl_xor(pick, off));
        const unsigned digit = (unsigned)(pick >> 16);
        kk = pick & 0xFFFF;
        prefix |= digit << shift;
        pmask  |= 0xFFu << shift;
        if (pass == 0) __syncthreads();
    }

    const unsigned short tu = (prefix & 0x8000u) ? (unsigned short)(prefix & 0x7FFFu)
                                                 : (unsigned short)((~prefix) & 0xFFFFu);
    const float thr = __half2float(__ushort_as_half(tu));

    float lg[16];
    float mx = -3.4e38f;
    #pragma unroll
    for (int i = 0; i < 16; ++i) {
        const float v = __half2float(__ushort_as_half(vs[i]));
        const float a = (v < thr) ? -1e-7f : v;
        lg[i] = a * (1.0f / 0.3f);
        mx = fmaxf(mx, lg[i]);
    }
    #pragma unroll
    for (int off = 32; off > 0; off >>= 1) mx = fmaxf(mx, __shfl_xor(mx, off));

    float e[16];
    float sum = 0.f;
    #pragma unroll
    for (int i = 0; i < 16; ++i) { e[i] = __expf(lg[i] - mx); sum += e[i]; }
    #pragma unroll
    for (int off = 32; off > 0; off >>= 1) sum += __shfl_xor(sum, off);
    const float inv = 1.0f / sum;

    unsigned short os[16];
    #pragma unroll
    for (int i = 0; i < 16; ++i) os[i] = f2bf(e[i] * inv);
    uint4* q = (uint4*)(attn + row * 1024 + lane * 16);
    q[0] = *(const uint4*)&os[0];
    q[1] = *(const uint4*)&os[8];
}

extern "C" void kernel_launch(void* const* d_in, const int* in_sizes, int n_in,
                              void* d_out, int out_size, void* d_ws, size_t ws_size,
                              hipStream_t stream) {
    (void)in_sizes; (void)n_in; (void)out_size; (void)ws_size;

    const float* h      = (const float*)d_in[0];  // 8x1024x320
    const float* Wqk    = (const float*)d_in[1];  // 320x640
    const float* bqk    = (const float*)d_in[2];  // 640
    const float* weight = (const float*)d_in[3];  // 320x320
    const float* bias   = (const float*)d_in[4];  // 320
    float* out = (float*)d_out;                   // 8192x320

    // workspace layout
    char* p = (char*)d_ws;
    __half*         at      = (__half*)p;         p += 8388608L * 2;   // 16 MB
    unsigned short* attn    = (unsigned short*)p; p += 8388608L * 2;   // 16 MB
    unsigned short* h_hi    = (unsigned short*)p; p += 2621440L * 2;
    unsigned short* h_lo    = (unsigned short*)p; p += 2621440L * 2;
    __half*         Q       = (__half*)p;         p += 2621440L * 2;
    __half*         Kb      = (__half*)p;         p += 2621440L * 2;
    unsigned short* WqkThi  = (unsigned short*)p; p += 204800L * 2;
    unsigned short* WqkTlo  = (unsigned short*)p; p += 204800L * 2;
    unsigned short* wT      = (unsigned short*)p; p += 384L * 320 * 2; // padded to 384 rows
    unsigned short* hWT     = (unsigned short*)p; p += 384L * 8192 * 2;

    // --- prep ---
    split2<<<2560, 256, 0, stream>>>((const float4*)h, (ushort4*)h_hi, (ushort4*)h_lo);
    transpose_split<true><<<dim3(20, 10, 1), 256, 0, stream>>>(
        Wqk, WqkThi, WqkTlo, 640, 320);
    transpose_split<false><<<dim3(10, 10, 1), 256, 0, stream>>>(
        weight, wT, nullptr, 320, 320);

    // --- hWT = wT @ h^T : [384pad][320] x [8192][320]^T -> bf16 [384][8192]
    //     (rows 320..383 are poison-fed and never read downstream)
    gemm_nt<false, 2, false><<<dim3(128, 3, 1), 256, 0, stream>>>(
        wT, nullptr, h_hi, nullptr, hWT, nullptr, nullptr,
        320, 320, 320, 8192, 0, 0, 0, 1.0f);

    // --- G1: qk = h@Wqk + bqk -> Q,K (fp16), bf16x3 compute ---
    gemm_nt<true, 1, false><<<dim3(10, 64, 1), 256, 0, stream>>>(
        h_hi, h_lo, WqkThi, WqkTlo, Q, Kb, bqk,
        320, 320, 320, 320, 0, 0, 0, 1.0f);

    // --- G2: at = 0.125 * Q@K^T (plain fp16 MFMA, fp16 out) ---
    gemm_nt<false, 4, true><<<dim3(16, 8, 8), 256, 0, stream>>>(
        (const unsigned short*)Q, nullptr, (const unsigned short*)Kb, nullptr,
        at, nullptr, nullptr,
        320, 320, 320, 1024, 327680, 327680, 1048576, 0.125f);

    // --- topk + softmax -> attn (bf16); one wave per row ---
    topk_softmax<<<2048, 256, 0, stream>>>(at, attn);

    // --- G4': out = attn @ hWT^T + bias (fp32) ---
    gemm_nt<false, 3, false><<<dim3(5, 8, 8), 256, 0, stream>>>(
        attn, nullptr, hWT, nullptr, out, nullptr, bias,
        1024, 1024, 8192, 320, 1048576, 1024, 327680, 1.0f);
}

// Round 6
// 160.120 us; speedup vs baseline: 3.8134x; 1.0286x over previous
//
#include <hip/hip_runtime.h>
#include <hip/hip_fp16.h>

// ---------------------------------------------------------------------------
// B=8, N=1024, F=320, H=5 (heads collapse: at = (Q·K^T)/8)
// R5: uniform fp16 datapath.
//   G1' (fp16, N=960): h16 @ [WqkT;weightT]^T -> cols<640: +bqk, deinterleave
//        -> Q,K fp16; cols>=640: transposed store -> hWT[320][8192] fp16.
//   G2  (fp16): at = 0.125 * Q@K^T -> fp16
//   topk_softmax: exact 171st-largest (2-pass radix, 16-bit keys) -> attn fp16
//   G4' (fp16): out = attn @ hWT^T + bias (fp32)   [uses out=attn@(h@weight)]
// Error budget: fp16 G1 compute adds ~1e-3 to at (same order as fp16 at
// storage quantum accepted in R3); hW/attn fp16 are MORE precise than bf16.
// ---------------------------------------------------------------------------

typedef __attribute__((ext_vector_type(8))) _Float16 half8;
typedef __attribute__((ext_vector_type(4))) float f32x4;

// ---- stage a (nrow16*16) x 32 fp16 tile (row-major, ld elems) into LDS -----
__device__ __forceinline__ void stage_tile(const __half* g, __half* lds,
                                           int nrow16, int ld, int wave, int lane) {
    const int r = lane >> 2;
    const int c = (lane & 3) * 8;
    for (int i = wave; i < nrow16; i += 4) {
        const __half* src = g + (long)(i * 16 + r) * ld + c;
        __builtin_amdgcn_global_load_lds(
            (const __attribute__((address_space(1))) unsigned int*)src,
            (__attribute__((address_space(3))) unsigned int*)(lds + i * 512),
            16, 0, 0);
    }
}

// ---------------------------------------------------------------------------
// NT fp16 MFMA GEMM: C[m][n] = alpha * sum_k A[m][k]*B[n][k] (+epilogue)
// BM=128, BN=64, BK=32; 256 threads = 4 waves (2x2), 64x32 per wave.
// EPI: 1 = G1': col<640 -> +bqk, deinterleave Q/K fp16; col>=640 ->
//              hWT[(col-640)][row] fp16 (transposed store, ld 8192)
//      3 = fp32 store + bias, batch-strided        [G4' -> out]
//      4 = fp16 store (alpha)                      [G2 -> at]
// ---------------------------------------------------------------------------
template <int EPI>
__global__ __launch_bounds__(256) void gemm_nt(
    const __half* __restrict__ A, const __half* __restrict__ B,
    void* __restrict__ C, void* __restrict__ C2, void* __restrict__ C3,
    const float* __restrict__ bias,
    int K, int lda, int ldb, int ldc,
    long sA, long sB, long sC, float alpha)
{
    constexpr int A_EL = 128 * 32;
    constexpr int B_EL = 64 * 32;
    __shared__ __half smem[A_EL + B_EL];
    __half* sA_ = smem;
    __half* sB_ = smem + A_EL;

    const int tid  = threadIdx.x;
    const int lane = tid & 63;
    const int wave = tid >> 6;
    const int wm   = wave >> 1;   // 0..1
    const int wn   = wave & 1;    // 0..1
    const int bz   = blockIdx.z;

    const __half* Ab = A + bz * sA + (long)blockIdx.y * 128 * lda;
    const __half* Bb = B + bz * sB + (long)blockIdx.x * 64 * ldb;

    f32x4 acc[4][2];
    #pragma unroll
    for (int i = 0; i < 4; ++i)
        #pragma unroll
        for (int j = 0; j < 2; ++j) acc[i][j] = (f32x4){0.f, 0.f, 0.f, 0.f};

    const int lrow = lane & 15;
    const int quad = lane >> 4;

    for (int k0 = 0; k0 < K; k0 += 32) {
        stage_tile(Ab + k0, sA_, 8, lda, wave, lane);
        stage_tile(Bb + k0, sB_, 4, ldb, wave, lane);
        __syncthreads();

        const __half* pA = sA_ + (wm * 64 + lrow) * 32 + quad * 8;
        const __half* pB = sB_ + (wn * 32 + lrow) * 32 + quad * 8;
        half8 ah[4], bh[2];
        #pragma unroll
        for (int mt = 0; mt < 4; ++mt) ah[mt] = *(const half8*)(pA + mt * 512);
        #pragma unroll
        for (int nt = 0; nt < 2; ++nt) bh[nt] = *(const half8*)(pB + nt * 512);
        #pragma unroll
        for (int mt = 0; mt < 4; ++mt)
            #pragma unroll
            for (int nt = 0; nt < 2; ++nt)
                acc[mt][nt] = __builtin_amdgcn_mfma_f32_16x16x32_f16(
                    ah[mt], bh[nt], acc[mt][nt], 0, 0, 0);
        __syncthreads();
    }

    // epilogue: C[row][col]; col = lane&15 within 16-tile, row = quad*4 + r
    const int row_base = blockIdx.y * 128 + wm * 64;
    const int col_base = blockIdx.x * 64 + wn * 32;
    #pragma unroll
    for (int mt = 0; mt < 4; ++mt)
        #pragma unroll
        for (int nt = 0; nt < 2; ++nt)
            #pragma unroll
            for (int r = 0; r < 4; ++r) {
                const int row = row_base + mt * 16 + quad * 4 + r;
                const int col = col_base + nt * 16 + lrow;
                const float v = acc[mt][nt][r];
                if (EPI == 1) {
                    if (col < 640) {
                        const float val = v + bias[col];
                        const long idx = (long)row * 320 + (col >> 1);
                        if (col & 1) ((__half*)C2)[idx] = __float2half(val);
                        else         ((__half*)C)[idx]  = __float2half(val);
                    } else {
                        ((__half*)C3)[(long)(col - 640) * 8192 + row] = __float2half(v);
                    }
                } else if (EPI == 3) {
                    ((float*)C)[bz * sC + (long)row * ldc + col] = v + bias[col];
                } else {  // EPI == 4
                    ((__half*)C)[bz * sC + (long)row * ldc + col] =
                        __float2half(alpha * v);
                }
            }
}

// ---- elementwise convert fp32 -> fp16 --------------------------------------
__global__ __launch_bounds__(256) void conv_f16(const float4* __restrict__ src,
                                                ushort4* __restrict__ dst)
{
    const int i = blockIdx.x * 256 + threadIdx.x;
    const float4 v = src[i];
    ushort4 o;
    o.x = __half_as_ushort(__float2half(v.x));
    o.y = __half_as_ushort(__float2half(v.y));
    o.z = __half_as_ushort(__float2half(v.z));
    o.w = __half_as_ushort(__float2half(v.w));
    dst[i] = o;
}

// ---- 32x32 tiled transpose fp32 -> fp16 ------------------------------------
__global__ __launch_bounds__(256) void transpose_f16(
    const float* __restrict__ src, __half* __restrict__ dst, int ldS, int ldT)
{
    __shared__ float t[32][33];
    const int c0 = blockIdx.x * 32, r0 = blockIdx.y * 32;
    const int lx = threadIdx.x & 31, ly = threadIdx.x >> 5;
    #pragma unroll
    for (int i = 0; i < 4; ++i)
        t[ly + 8 * i][lx] = src[(long)(r0 + ly + 8 * i) * ldS + c0 + lx];
    __syncthreads();
    #pragma unroll
    for (int i = 0; i < 4; ++i)
        dst[(long)(c0 + ly + 8 * i) * ldT + r0 + lx] = __float2half(t[lx][ly + 8 * i]);
}

// ---------------------------------------------------------------------------
// Exact 171st-largest per row of 1024 fp16 values: 2-pass radix select on
// 16-bit order-preserving keys. One wave per row (4 rows / block).
// Writes attn as fp16.
// ---------------------------------------------------------------------------
__global__ __launch_bounds__(256) void topk_softmax(const __half* __restrict__ at,
                                                    __half* __restrict__ attn)
{
    __shared__ int hist[4][256];
    const int lane = threadIdx.x & 63;
    const int wave = threadIdx.x >> 6;
    const long row = (long)blockIdx.x * 4 + wave;

    unsigned short vs[16];
    {
        const uint4* p = (const uint4*)(at + row * 1024 + lane * 16);
        *(uint4*)&vs[0] = p[0];
        *(uint4*)&vs[8] = p[1];
    }

    unsigned key[16];
    #pragma unroll
    for (int i = 0; i < 16; ++i) {
        const unsigned u = vs[i];
        key[i] = (u & 0x8000u) ? ((~u) & 0xFFFFu) : (u | 0x8000u);
    }

    unsigned prefix = 0, pmask = 0;
    int kk = 171;

    #pragma unroll
    for (int pass = 0; pass < 2; ++pass) {
        const int shift = 8 - 8 * pass;
        *(int4*)&hist[wave][lane * 4] = make_int4(0, 0, 0, 0);
        __syncthreads();
        #pragma unroll
        for (int i = 0; i < 16; ++i) {
            if ((key[i] & pmask) == prefix)
                atomicAdd(&hist[wave][(key[i] >> shift) & 255], 1);
        }
        __syncthreads();
        const int4 hh = *(const int4*)&hist[wave][lane * 4];
        const int s = hh.x + hh.y + hh.z + hh.w;
        int suf = s;
        #pragma unroll
        for (int off = 1; off < 64; off <<= 1) {
            const int o = __shfl_down(suf, off);
            if (lane + off < 64) suf += o;
        }
        const int cgt3 = suf - s;
        const int cgt2 = cgt3 + hh.w;
        const int cgt1 = cgt2 + hh.z;
        const int cgt0 = cgt1 + hh.y;
        int pick = 0x7FFFFFFF;
        if (cgt3 < kk && kk <= cgt3 + hh.w) pick = ((4 * lane + 3) << 16) | (kk - cgt3);
        if (cgt2 < kk && kk <= cgt2 + hh.z) pick = ((4 * lane + 2) << 16) | (kk - cgt2);
        if (cgt1 < kk && kk <= cgt1 + hh.y) pick = ((4 * lane + 1) << 16) | (kk - cgt1);
        if (cgt0 < kk && kk <= cgt0 + hh.x) pick = ((4 * lane + 0) << 16) | (kk - cgt0);
        #pragma unroll
        for (int off = 32; off > 0; off >>= 1) pick = min(pick, __shfl_xor(pick, off));
        const unsigned digit = (unsigned)(pick >> 16);
        kk = pick & 0xFFFF;
        prefix |= digit << shift;
        pmask  |= 0xFFu << shift;
        if (pass == 0) __syncthreads();
    }

    const unsigned short tu = (prefix & 0x8000u) ? (unsigned short)(prefix & 0x7FFFu)
                                                 : (unsigned short)((~prefix) & 0xFFFFu);
    const float thr = __half2float(__ushort_as_half(tu));

    float lg[16];
    float mx = -3.4e38f;
    #pragma unroll
    for (int i = 0; i < 16; ++i) {
        const float v = __half2float(__ushort_as_half(vs[i]));
        const float a = (v < thr) ? -1e-7f : v;
        lg[i] = a * (1.0f / 0.3f);
        mx = fmaxf(mx, lg[i]);
    }
    #pragma unroll
    for (int off = 32; off > 0; off >>= 1) mx = fmaxf(mx, __shfl_xor(mx, off));

    float e[16];
    float sum = 0.f;
    #pragma unroll
    for (int i = 0; i < 16; ++i) { e[i] = __expf(lg[i] - mx); sum += e[i]; }
    #pragma unroll
    for (int off = 32; off > 0; off >>= 1) sum += __shfl_xor(sum, off);
    const float inv = 1.0f / sum;

    unsigned short os[16];
    #pragma unroll
    for (int i = 0; i < 16; ++i) os[i] = __half_as_ushort(__float2half(e[i] * inv));
    uint4* q = (uint4*)(attn + row * 1024 + lane * 16);
    q[0] = *(const uint4*)&os[0];
    q[1] = *(const uint4*)&os[8];
}

extern "C" void kernel_launch(void* const* d_in, const int* in_sizes, int n_in,
                              void* d_out, int out_size, void* d_ws, size_t ws_size,
                              hipStream_t stream) {
    (void)in_sizes; (void)n_in; (void)out_size; (void)ws_size;

    const float* h      = (const float*)d_in[0];  // 8x1024x320
    const float* Wqk    = (const float*)d_in[1];  // 320x640
    const float* bqk    = (const float*)d_in[2];  // 640
    const float* weight = (const float*)d_in[3];  // 320x320
    const float* bias   = (const float*)d_in[4];  // 320
    float* out = (float*)d_out;                   // 8192x320

    // workspace layout
    char* p = (char*)d_ws;
    __half* at   = (__half*)p; p += 8388608L * 2;        // 16 MB
    __half* attn = (__half*)p; p += 8388608L * 2;        // 16 MB
    __half* h16  = (__half*)p; p += 2621440L * 2;        // 5 MB
    __half* Q    = (__half*)p; p += 2621440L * 2;        // 5 MB
    __half* Kb   = (__half*)p; p += 2621440L * 2;        // 5 MB
    __half* BT   = (__half*)p; p += 960L * 320 * 2;      // [WqkT;weightT] 600 KB
    __half* hWT  = (__half*)p; p += 320L * 8192 * 2;     // 5 MB

    // --- prep: h -> fp16; B' = [WqkT (640 rows) ; weightT (320 rows)] ---
    conv_f16<<<2560, 256, 0, stream>>>((const float4*)h, (ushort4*)h16);
    transpose_f16<<<dim3(20, 10, 1), 256, 0, stream>>>(Wqk, BT, 640, 320);
    transpose_f16<<<dim3(10, 10, 1), 256, 0, stream>>>(weight, BT + 640L * 320, 320, 320);

    // --- G1': h16 @ B'^T (N=960) -> Q,K fp16 (+bqk) and hWT[320][8192] ---
    gemm_nt<1><<<dim3(15, 64, 1), 256, 0, stream>>>(
        h16, BT, Q, Kb, hWT, bqk,
        320, 320, 320, 0, 0, 0, 0, 1.0f);

    // --- G2: at = 0.125 * Q@K^T (fp16 out) ---
    gemm_nt<4><<<dim3(16, 8, 8), 256, 0, stream>>>(
        Q, Kb, at, nullptr, nullptr, nullptr,
        320, 320, 320, 1024, 327680, 327680, 1048576, 0.125f);

    // --- topk + softmax -> attn (fp16); one wave per row ---
    topk_softmax<<<2048, 256, 0, stream>>>(at, attn);

    // --- G4': out = attn @ hWT^T + bias (fp32) ---
    gemm_nt<3><<<dim3(5, 8, 8), 256, 0, stream>>>(
        attn, hWT, out, nullptr, nullptr, bias,
        1024, 1024, 8192, 320, 1048576, 1024, 327680, 1.0f);
}